// Round 5
// baseline (2389.047 us; speedup 1.0000x reference)
//
#include <hip/hip_runtime.h>
#include <math.h>

#define FEAT 64
#define CHEB_M 30
#define T_SCALE_D 5.0
#define TILE 1024

// ---------------- CSR build ----------------
// Diagonal entries (row==col) are accumulated into a dense diag[] array and
// excluded from the CSR (general for any COO). Off-diagonal rows padded to a
// multiple of 8 with {col=0, val=0} entries. After scatter, each row's edges
// are sorted by column so all resident waves sweep columns in the same order
// (narrow active column window -> per-XCD L2 hits instead of fabric traffic).

__global__ void hist_kernel(const int* __restrict__ rows, const int* __restrict__ cols,
                            const float* __restrict__ vals, int* __restrict__ counts,
                            float* __restrict__ diag, int nnz) {
    int i = blockIdx.x * blockDim.x + threadIdx.x;
    int stride = gridDim.x * blockDim.x;
    for (; i < nnz; i += stride) {
        int r = rows[i];
        if (r == cols[i]) atomicAdd(&diag[r], vals[i]);
        else atomicAdd(&counts[r], 1);
    }
}

#define PAD8(c) (((c) + 7) & ~7)

// Pass A: per-1024-tile sums of PADDED counts
__global__ __launch_bounds__(256) void tile_reduce_kernel(const int* __restrict__ counts,
                                                          int* __restrict__ tile_sums, int N) {
    __shared__ int lds[256];
    int base = blockIdx.x * TILE;
    int t = threadIdx.x;
    int sum = 0;
    for (int i = t; i < TILE; i += 256) {
        int idx = base + i;
        if (idx < N) sum += PAD8(counts[idx]);
    }
    lds[t] = sum;
    __syncthreads();
    for (int off = 128; off > 0; off >>= 1) {
        if (t < off) lds[t] += lds[t + off];
        __syncthreads();
    }
    if (t == 0) tile_sums[blockIdx.x] = lds[0];
}

// Pass B: single-block scan of tile sums -> exclusive tile offsets + total
__global__ __launch_bounds__(1024) void tile_scan_kernel(const int* __restrict__ tile_sums,
                                                         int* __restrict__ tile_off,
                                                         int* __restrict__ row_ptr_last, int T) {
    __shared__ int lds[1024];
    int t = threadIdx.x;
    int v = (t < T) ? tile_sums[t] : 0;
    lds[t] = v;
    __syncthreads();
    for (int off = 1; off < 1024; off <<= 1) {
        int add = (t >= off) ? lds[t - off] : 0;
        __syncthreads();
        lds[t] += add;
        __syncthreads();
    }
    tile_off[t] = (t == 0) ? 0 : lds[t - 1];
    if (t == 0) *row_ptr_last = lds[1023];
}

// Pass C: per-tile exclusive scan of PADDED counts -> row_ptr, cursor
__global__ __launch_bounds__(1024) void tile_apply_kernel(const int* __restrict__ counts,
                                                          const int* __restrict__ tile_off,
                                                          int* __restrict__ row_ptr,
                                                          int* __restrict__ cursor, int N) {
    __shared__ int lds[1024];
    int base = blockIdx.x * TILE;
    int t = threadIdx.x;
    int idx = base + t;
    int v = (idx < N) ? PAD8(counts[idx]) : 0;
    lds[t] = v;
    __syncthreads();
    for (int off = 1; off < 1024; off <<= 1) {
        int add = (t >= off) ? lds[t - off] : 0;
        __syncthreads();
        lds[t] += add;
        __syncthreads();
    }
    if (idx < N) {
        int excl = tile_off[blockIdx.x] + lds[t] - v;  // inclusive - self
        row_ptr[idx] = excl;
        cursor[idx] = excl;
    }
}

// Scatter off-diagonal entries into packed {col, val-bits}. cv pre-memset to
// 0, so padding slots are {col=0, val=0.0f} (harmless: gather X[0], FMA 0).
__global__ void scatter_kernel(const int* __restrict__ rows, const int* __restrict__ cols,
                               const float* __restrict__ vals, int* __restrict__ cursor,
                               int2* __restrict__ cv, int nnz) {
    int i = blockIdx.x * blockDim.x + threadIdx.x;
    int stride = gridDim.x * blockDim.x;
    for (; i < nnz; i += stride) {
        int r = rows[i];
        int c = cols[i];
        if (r == c) continue;
        int p = atomicAdd(&cursor[r], 1);
        cv[p] = make_int2(c, __float_as_int(vals[i]));
    }
}

// In-place per-row insertion sort by column. One thread per row; rows are
// short (avg deg ~16). L2-resident traffic, runs once, pays off x29 steps.
__global__ __launch_bounds__(256) void sort_rows_kernel(const int* __restrict__ row_ptr,
                                                        const int* __restrict__ counts,
                                                        int2* __restrict__ cv, int N) {
    int r = blockIdx.x * blockDim.x + threadIdx.x;
    if (r >= N) return;
    int e0 = row_ptr[r];
    int cnt = counts[r];
    for (int i = 1; i < cnt; ++i) {
        int2 key = cv[e0 + i];
        int k = i - 1;
        while (k >= 0) {
            int2 cur = cv[e0 + k];
            if (cur.x <= key.x) break;
            cv[e0 + k + 1] = cur;
            --k;
        }
        cv[e0 + k + 1] = key;
    }
}

// ---------------- Chebyshev steps ----------------
// One row per 64-lane wave (4 rows per 256-thread block). Lane j owns feature
// j; each edge gather is one coalesced 256B read of SRC[col][0:64]. Rows are
// padded to multiples of 8; main loop is 16-wide, remainder 8-wide.
// lmul(Y)[r] = sum_offdiag val*Y[col] + (diag[r]-1)*Y[r].

#define GLOAD(K)  float g##K = SRC[(((unsigned)a##K.x) << 6) | j];
#define GFMA(K)   s = fmaf(__int_as_float(a##K.y), g##K, s);

#define GATHER8(SRC)                                                          \
    {                                                                         \
        int2 a0 = cv[e], a1 = cv[e + 1], a2 = cv[e + 2], a3 = cv[e + 3];      \
        int2 a4 = cv[e + 4], a5 = cv[e + 5], a6 = cv[e + 6], a7 = cv[e + 7];  \
        GLOAD(0) GLOAD(1) GLOAD(2) GLOAD(3) GLOAD(4) GLOAD(5) GLOAD(6) GLOAD(7) \
        GFMA(0) GFMA(1) GFMA(2) GFMA(3) GFMA(4) GFMA(5) GFMA(6) GFMA(7)       \
    }

#define GATHER16(SRC)                                                         \
    {                                                                         \
        int2 a0 = cv[e], a1 = cv[e + 1], a2 = cv[e + 2], a3 = cv[e + 3];      \
        int2 a4 = cv[e + 4], a5 = cv[e + 5], a6 = cv[e + 6], a7 = cv[e + 7];  \
        int2 a8 = cv[e + 8], a9 = cv[e + 9], a10 = cv[e + 10], a11 = cv[e + 11]; \
        int2 a12 = cv[e + 12], a13 = cv[e + 13], a14 = cv[e + 14], a15 = cv[e + 15]; \
        GLOAD(0) GLOAD(1) GLOAD(2) GLOAD(3) GLOAD(4) GLOAD(5) GLOAD(6) GLOAD(7) \
        GLOAD(8) GLOAD(9) GLOAD(10) GLOAD(11) GLOAD(12) GLOAD(13) GLOAD(14) GLOAD(15) \
        GFMA(0) GFMA(1) GFMA(2) GFMA(3) GFMA(4) GFMA(5) GFMA(6) GFMA(7)       \
        GFMA(8) GFMA(9) GFMA(10) GFMA(11) GFMA(12) GFMA(13) GFMA(14) GFMA(15) \
    }

// First step: T1 = lmul(X); acc = c0*X + c1*T1 (acc fully overwritten)
__global__ __launch_bounds__(256) void cheb_first(
        const float* __restrict__ X, float* __restrict__ t1buf,
        float* __restrict__ acc, const int* __restrict__ row_ptr,
        const int2* __restrict__ cv, const float* __restrict__ diag,
        float c0, float c1, int N) {
    int r = (blockIdx.x << 2) + (threadIdx.x >> 6);
    if (r >= N) return;
    unsigned j = threadIdx.x & 63;
    int e0 = __builtin_amdgcn_readfirstlane(row_ptr[r]);
    int e1 = __builtin_amdgcn_readfirstlane(row_ptr[r + 1]);
    float dm1 = diag[r] - 1.0f;
    float s = 0.f;
    int e = e0;
    {
        const float* __restrict__ SRC = X;
        for (; e + 16 <= e1; e += 16) GATHER16(SRC);
        if (e < e1) GATHER8(SRC);  // padded to 8 -> remainder is exactly 8
    }
    unsigned idx = (((unsigned)r) << 6) | j;
    float xr = X[idx];
    float t1 = fmaf(dm1, xr, s);
    t1buf[idx] = t1;
    acc[idx] = c0 * xr + c1 * t1;
}

// Generic step: tk = 2*lmul(t1) - t0; acc += ck*tk; tnew = tk.
// tnew may alias t0 (in-place ping-pong) -> t0/tnew NOT restrict; each t0
// element is read only by the exact thread that writes tnew there.
__global__ __launch_bounds__(256) void cheb_step(
        const float* t0, const float* __restrict__ t1,
        float* tnew, float* __restrict__ acc,
        const int* __restrict__ row_ptr, const int2* __restrict__ cv,
        const float* __restrict__ diag, float ck, int N) {
    int r = (blockIdx.x << 2) + (threadIdx.x >> 6);
    if (r >= N) return;
    unsigned j = threadIdx.x & 63;
    int e0 = __builtin_amdgcn_readfirstlane(row_ptr[r]);
    int e1 = __builtin_amdgcn_readfirstlane(row_ptr[r + 1]);
    float dm1 = diag[r] - 1.0f;
    float s = 0.f;
    int e = e0;
    {
        const float* __restrict__ SRC = t1;
        for (; e + 16 <= e1; e += 16) GATHER16(SRC);
        if (e < e1) GATHER8(SRC);
    }
    unsigned idx = (((unsigned)r) << 6) | j;
    float t1r = t1[idx];
    float t0r = t0[idx];
    float tk = 2.f * fmaf(dm1, t1r, s) - t0r;
    tnew[idx] = tk;
    acc[idx] += ck * tk;
}

extern "C" void kernel_launch(void* const* d_in, const int* in_sizes, int n_in,
                              void* d_out, int out_size, void* d_ws, size_t ws_size,
                              hipStream_t stream) {
    const int* rows = (const int*)d_in[0];
    const int* cols = (const int*)d_in[1];
    const float* vals = (const float*)d_in[2];
    const float* X = (const float*)d_in[3];
    int nnz = in_sizes[0];
    int Nd = in_sizes[3];
    int N = Nd / FEAT;
    float* acc = (float*)d_out;

    char* ws = (char*)d_ws;
    float* B0 = (float*)ws;
    float* B1 = (float*)(ws + (size_t)Nd * 4);
    int* row_ptr = (int*)(ws + (size_t)Nd * 8);       // N+1
    int* cursor = row_ptr + (N + 1);                  // N
    int* counts = cursor + N;                         // N
    int* tile_sums = counts + N;                      // 1024
    int* tile_off = tile_sums + 1024;                 // 1024
    float* diag = (float*)(tile_off + 1024);          // N
    int2* cv = (int2*)(diag + N);
    cv = (int2*)((((size_t)cv) + 7) & ~(size_t)7);    // 8B align
    // padded capacity: every row can add up to 7 padding slots
    size_t cv_entries = (size_t)nnz + 7 * (size_t)N + 8;

    // Static Chebyshev coefficients for exp(-t_scale * lambda), lambda_max=2.
    double c[CHEB_M];
    for (int k = 0; k < CHEB_M; ++k) {
        double sum = 0.0;
        for (int jj = 0; jj < CHEB_M; ++jj) {
            double theta = M_PI * (jj + 0.5) / CHEB_M;
            double lam = cos(theta) + 1.0;  // lambda_max/2 * (x+1)
            sum += exp(-T_SCALE_D * lam) * cos(k * theta);
        }
        c[k] = 2.0 / CHEB_M * sum;
    }
    c[0] *= 0.5;

    int T = (N + TILE - 1) / TILE;  // <= 1024 supported

    // CSR build (every launch)
    hipMemsetAsync(counts, 0, (size_t)N * sizeof(int), stream);
    hipMemsetAsync(diag, 0, (size_t)N * sizeof(float), stream);
    hipMemsetAsync(cv, 0, cv_entries * sizeof(int2), stream);  // padding = {0,0}
    hist_kernel<<<2048, 256, 0, stream>>>(rows, cols, vals, counts, diag, nnz);
    tile_reduce_kernel<<<T, 256, 0, stream>>>(counts, tile_sums, N);
    tile_scan_kernel<<<1, 1024, 0, stream>>>(tile_sums, tile_off, &row_ptr[N], T);
    tile_apply_kernel<<<T, 1024, 0, stream>>>(counts, tile_off, row_ptr, cursor, N);
    scatter_kernel<<<2048, 256, 0, stream>>>(rows, cols, vals, cursor, cv, nnz);
    sort_rows_kernel<<<(N + 255) / 256, 256, 0, stream>>>(row_ptr, counts, cv, N);

    int nblk = (N + 3) >> 2;
    // k = 0,1 fused
    cheb_first<<<nblk, 256, 0, stream>>>(X, B0, acc, row_ptr, cv, diag,
                                         (float)c[0], (float)c[1], N);
    // k = 2: t0 = X (read-only input), t1 = B0, write B1
    cheb_step<<<nblk, 256, 0, stream>>>(X, B0, B1, acc, row_ptr, cv, diag,
                                        (float)c[2], N);
    // k >= 3: tk overwrites the t0 buffer in place, then swap roles
    const float* t0p = B0;
    const float* t1p = B1;
    for (int k = 3; k < CHEB_M; ++k) {
        cheb_step<<<nblk, 256, 0, stream>>>(t0p, t1p, (float*)t0p, acc, row_ptr,
                                            cv, diag, (float)c[k], N);
        const float* tmp = t0p; t0p = t1p; t1p = tmp;
    }
}

// Round 6
// 2216.476 us; speedup vs baseline: 1.0779x; 1.0779x over previous
//
#include <hip/hip_runtime.h>
#include <math.h>

#define FEAT 64
#define CHEB_M 30
#define T_SCALE_D 5.0
#define TILE 1024
#define RPW 28          // rows per wave in the persistent kernel
#define NUM_CU 256      // gfx950 / MI355X

// ---------------- CSR build ----------------
// Diagonal entries (row==col) accumulate into dense diag[]; off-diagonal rows
// padded to a multiple of 8 with {col=0, val=0} entries.

__global__ void hist_kernel(const int* __restrict__ rows, const int* __restrict__ cols,
                            const float* __restrict__ vals, int* __restrict__ counts,
                            float* __restrict__ diag, int nnz) {
    int i = blockIdx.x * blockDim.x + threadIdx.x;
    int stride = gridDim.x * blockDim.x;
    for (; i < nnz; i += stride) {
        int r = rows[i];
        if (r == cols[i]) atomicAdd(&diag[r], vals[i]);
        else atomicAdd(&counts[r], 1);
    }
}

#define PAD8(c) (((c) + 7) & ~7)

__global__ __launch_bounds__(256) void tile_reduce_kernel(const int* __restrict__ counts,
                                                          int* __restrict__ tile_sums, int N) {
    __shared__ int lds[256];
    int base = blockIdx.x * TILE;
    int t = threadIdx.x;
    int sum = 0;
    for (int i = t; i < TILE; i += 256) {
        int idx = base + i;
        if (idx < N) sum += PAD8(counts[idx]);
    }
    lds[t] = sum;
    __syncthreads();
    for (int off = 128; off > 0; off >>= 1) {
        if (t < off) lds[t] += lds[t + off];
        __syncthreads();
    }
    if (t == 0) tile_sums[blockIdx.x] = lds[0];
}

__global__ __launch_bounds__(1024) void tile_scan_kernel(const int* __restrict__ tile_sums,
                                                         int* __restrict__ tile_off,
                                                         int* __restrict__ row_ptr_last, int T) {
    __shared__ int lds[1024];
    int t = threadIdx.x;
    int v = (t < T) ? tile_sums[t] : 0;
    lds[t] = v;
    __syncthreads();
    for (int off = 1; off < 1024; off <<= 1) {
        int add = (t >= off) ? lds[t - off] : 0;
        __syncthreads();
        lds[t] += add;
        __syncthreads();
    }
    tile_off[t] = (t == 0) ? 0 : lds[t - 1];
    if (t == 0) *row_ptr_last = lds[1023];
}

__global__ __launch_bounds__(1024) void tile_apply_kernel(const int* __restrict__ counts,
                                                          const int* __restrict__ tile_off,
                                                          int* __restrict__ row_ptr,
                                                          int* __restrict__ cursor, int N) {
    __shared__ int lds[1024];
    int base = blockIdx.x * TILE;
    int t = threadIdx.x;
    int idx = base + t;
    int v = (idx < N) ? PAD8(counts[idx]) : 0;
    lds[t] = v;
    __syncthreads();
    for (int off = 1; off < 1024; off <<= 1) {
        int add = (t >= off) ? lds[t - off] : 0;
        __syncthreads();
        lds[t] += add;
        __syncthreads();
    }
    if (idx < N) {
        int excl = tile_off[blockIdx.x] + lds[t] - v;
        row_ptr[idx] = excl;
        cursor[idx] = excl;
    }
}

__global__ void scatter_kernel(const int* __restrict__ rows, const int* __restrict__ cols,
                               const float* __restrict__ vals, int* __restrict__ cursor,
                               int2* __restrict__ cv, int nnz) {
    int i = blockIdx.x * blockDim.x + threadIdx.x;
    int stride = gridDim.x * blockDim.x;
    for (; i < nnz; i += stride) {
        int r = rows[i];
        int c = cols[i];
        if (r == c) continue;
        int p = atomicAdd(&cursor[r], 1);
        cv[p] = make_int2(c, __float_as_int(vals[i]));
    }
}

// ---------------- gather core ----------------

#define GLOAD(K)  float g##K = SRC[(((unsigned)a##K.x) << 6) | j];
#define GFMA(K)   s = fmaf(__int_as_float(a##K.y), g##K, s);

#define GATHER8(SRC)                                                          \
    {                                                                         \
        int2 a0 = cv[e], a1 = cv[e + 1], a2 = cv[e + 2], a3 = cv[e + 3];      \
        int2 a4 = cv[e + 4], a5 = cv[e + 5], a6 = cv[e + 6], a7 = cv[e + 7];  \
        GLOAD(0) GLOAD(1) GLOAD(2) GLOAD(3) GLOAD(4) GLOAD(5) GLOAD(6) GLOAD(7) \
        GFMA(0) GFMA(1) GFMA(2) GFMA(3) GFMA(4) GFMA(5) GFMA(6) GFMA(7)       \
    }

#define GATHER16(SRC)                                                         \
    {                                                                         \
        int2 a0 = cv[e], a1 = cv[e + 1], a2 = cv[e + 2], a3 = cv[e + 3];      \
        int2 a4 = cv[e + 4], a5 = cv[e + 5], a6 = cv[e + 6], a7 = cv[e + 7];  \
        int2 a8 = cv[e + 8], a9 = cv[e + 9], a10 = cv[e + 10], a11 = cv[e + 11]; \
        int2 a12 = cv[e + 12], a13 = cv[e + 13], a14 = cv[e + 14], a15 = cv[e + 15]; \
        GLOAD(0) GLOAD(1) GLOAD(2) GLOAD(3) GLOAD(4) GLOAD(5) GLOAD(6) GLOAD(7) \
        GLOAD(8) GLOAD(9) GLOAD(10) GLOAD(11) GLOAD(12) GLOAD(13) GLOAD(14) GLOAD(15) \
        GFMA(0) GFMA(1) GFMA(2) GFMA(3) GFMA(4) GFMA(5) GFMA(6) GFMA(7)       \
        GFMA(8) GFMA(9) GFMA(10) GFMA(11) GFMA(12) GFMA(13) GFMA(14) GFMA(15) \
    }

__device__ __forceinline__ float gather_row(const float* __restrict__ SRC,
                                            const int2* __restrict__ cv,
                                            int e0, int e1, unsigned j) {
    float s = 0.f;
    int e = e0;
    for (; e + 16 <= e1; e += 16) GATHER16(SRC);
    if (e < e1) GATHER8(SRC);  // rows padded to 8 -> remainder is exactly 8
    return s;
}

// ---------------- persistent all-steps kernel ----------------
// Each 64-lane wave statically owns RPW rows; lane j owns feature j. t0 and
// acc live in registers across all 29 steps; only t1 round-trips through
// memory (it must: it is the gather source for every other row). Grid-wide
// sense-reversing barrier between steps with agent-scope (device) atomics;
// launched only if all blocks are co-resident (host occupancy check).

struct Coeffs { float c[CHEB_M]; };

__device__ __forceinline__ void grid_barrier(unsigned* cnt, unsigned* gen, unsigned target) {
    __syncthreads();
    if (threadIdx.x == 0) {
        unsigned a = __hip_atomic_fetch_add(cnt, 1u, __ATOMIC_ACQ_REL,
                                            __HIP_MEMORY_SCOPE_AGENT);
        if (a == gridDim.x - 1) {
            __hip_atomic_store(cnt, 0u, __ATOMIC_RELAXED, __HIP_MEMORY_SCOPE_AGENT);
            __hip_atomic_store(gen, target, __ATOMIC_RELEASE, __HIP_MEMORY_SCOPE_AGENT);
        } else {
            while (__hip_atomic_load(gen, __ATOMIC_RELAXED, __HIP_MEMORY_SCOPE_AGENT) < target) {
                __builtin_amdgcn_s_sleep(2);
            }
        }
    }
    __syncthreads();
    // Invalidate stale L1/L2 lines of the buffer written by other XCDs.
    __builtin_amdgcn_fence(__ATOMIC_ACQUIRE, "agent");
}

__global__ __launch_bounds__(256, 4) void cheb_persistent(
        const float* __restrict__ X, float* __restrict__ bufA, float* __restrict__ bufB,
        float* __restrict__ out, const int* __restrict__ row_ptr,
        const int2* __restrict__ cv, const float* __restrict__ diag,
        unsigned* bar_cnt, unsigned* bar_gen, Coeffs co, int N) {
    int wid = (blockIdx.x << 2) + (threadIdx.x >> 6);
    unsigned j = threadIdx.x & 63;
    int rbase = wid * RPW;

    float t0v[RPW], accv[RPW];

    // ---- step k=1: T1 = lmul(X); acc = c0*X + c1*T1 ----
    {
        float c0 = co.c[0], c1 = co.c[1];
        #pragma unroll
        for (int rr = 0; rr < RPW; ++rr) {
            int r = rbase + rr;
            if (r < N) {
                int e0 = __builtin_amdgcn_readfirstlane(row_ptr[r]);
                int e1 = __builtin_amdgcn_readfirstlane(row_ptr[r + 1]);
                float s = gather_row(X, cv, e0, e1, j);
                unsigned idx = (((unsigned)r) << 6) | j;
                float xr = X[idx];
                float dm1 = diag[r] - 1.0f;
                float t1 = fmaf(dm1, xr, s);
                t0v[rr] = xr;
                accv[rr] = c0 * xr + c1 * t1;
                bufA[idx] = t1;
            }
        }
    }
    grid_barrier(bar_cnt, bar_gen, 1u);

    // ---- steps k=2..29: tk = 2*lmul(t1) - t0; acc += ck*tk ----
    for (int k = 2; k < CHEB_M; ++k) {
        const float* __restrict__ src = (k & 1) ? bufB : bufA;
        float* __restrict__ dst = (k & 1) ? bufA : bufB;
        float ck = co.c[k];
        #pragma unroll
        for (int rr = 0; rr < RPW; ++rr) {
            int r = rbase + rr;
            if (r < N) {
                int e0 = __builtin_amdgcn_readfirstlane(row_ptr[r]);
                int e1 = __builtin_amdgcn_readfirstlane(row_ptr[r + 1]);
                float s = gather_row(src, cv, e0, e1, j);
                unsigned idx = (((unsigned)r) << 6) | j;
                float t1r = src[idx];
                float dm1 = diag[r] - 1.0f;
                float tk = 2.0f * fmaf(dm1, t1r, s) - t0v[rr];
                accv[rr] = fmaf(ck, tk, accv[rr]);
                t0v[rr] = t1r;
                dst[idx] = tk;
            }
        }
        if (k < CHEB_M - 1) grid_barrier(bar_cnt, bar_gen, (unsigned)k);
    }

    // ---- epilogue: acc -> out ----
    #pragma unroll
    for (int rr = 0; rr < RPW; ++rr) {
        int r = rbase + rr;
        if (r < N) out[(((unsigned)r) << 6) | j] = accv[rr];
    }
}

// ---------------- fallback per-step kernels (proven round-4 path) ----------------

__global__ __launch_bounds__(256) void cheb_first(
        const float* __restrict__ X, float* __restrict__ t1buf,
        float* __restrict__ acc, const int* __restrict__ row_ptr,
        const int2* __restrict__ cv, const float* __restrict__ diag,
        float c0, float c1, int N) {
    int r = (blockIdx.x << 2) + (threadIdx.x >> 6);
    if (r >= N) return;
    unsigned j = threadIdx.x & 63;
    int e0 = __builtin_amdgcn_readfirstlane(row_ptr[r]);
    int e1 = __builtin_amdgcn_readfirstlane(row_ptr[r + 1]);
    float dm1 = diag[r] - 1.0f;
    float s = gather_row(X, cv, e0, e1, j);
    unsigned idx = (((unsigned)r) << 6) | j;
    float xr = X[idx];
    float t1 = fmaf(dm1, xr, s);
    t1buf[idx] = t1;
    acc[idx] = c0 * xr + c1 * t1;
}

__global__ __launch_bounds__(256) void cheb_step(
        const float* t0, const float* __restrict__ t1,
        float* tnew, float* __restrict__ acc,
        const int* __restrict__ row_ptr, const int2* __restrict__ cv,
        const float* __restrict__ diag, float ck, int N) {
    int r = (blockIdx.x << 2) + (threadIdx.x >> 6);
    if (r >= N) return;
    unsigned j = threadIdx.x & 63;
    int e0 = __builtin_amdgcn_readfirstlane(row_ptr[r]);
    int e1 = __builtin_amdgcn_readfirstlane(row_ptr[r + 1]);
    float dm1 = diag[r] - 1.0f;
    float s = gather_row(t1, cv, e0, e1, j);
    unsigned idx = (((unsigned)r) << 6) | j;
    float t1r = t1[idx];
    float t0r = t0[idx];
    float tk = 2.f * fmaf(dm1, t1r, s) - t0r;
    tnew[idx] = tk;
    acc[idx] += ck * tk;
}

extern "C" void kernel_launch(void* const* d_in, const int* in_sizes, int n_in,
                              void* d_out, int out_size, void* d_ws, size_t ws_size,
                              hipStream_t stream) {
    const int* rows = (const int*)d_in[0];
    const int* cols = (const int*)d_in[1];
    const float* vals = (const float*)d_in[2];
    const float* X = (const float*)d_in[3];
    int nnz = in_sizes[0];
    int Nd = in_sizes[3];
    int N = Nd / FEAT;
    float* acc = (float*)d_out;

    char* ws = (char*)d_ws;
    float* B0 = (float*)ws;
    float* B1 = (float*)(ws + (size_t)Nd * 4);
    int* row_ptr = (int*)(ws + (size_t)Nd * 8);       // N+1
    int* cursor = row_ptr + (N + 1);                  // N
    int* counts = cursor + N;                         // N
    int* tile_sums = counts + N;                      // 1024
    int* tile_off = tile_sums + 1024;                 // 1024
    unsigned* bar = (unsigned*)(tile_off + 1024);     // 2 (barrier cnt, gen)
    float* diag = (float*)(bar + 2);                  // N
    int2* cv = (int2*)(diag + N);
    cv = (int2*)((((size_t)cv) + 7) & ~(size_t)7);    // 8B align
    size_t cv_entries = (size_t)nnz + 7 * (size_t)N + 8;

    // Static Chebyshev coefficients for exp(-t_scale*lambda), lambda_max=2.
    double c[CHEB_M];
    for (int k = 0; k < CHEB_M; ++k) {
        double sum = 0.0;
        for (int jj = 0; jj < CHEB_M; ++jj) {
            double theta = M_PI * (jj + 0.5) / CHEB_M;
            double lam = cos(theta) + 1.0;
            sum += exp(-T_SCALE_D * lam) * cos(k * theta);
        }
        c[k] = 2.0 / CHEB_M * sum;
    }
    c[0] *= 0.5;
    Coeffs co;
    for (int k = 0; k < CHEB_M; ++k) co.c[k] = (float)c[k];

    int T = (N + TILE - 1) / TILE;

    // CSR build (every launch)
    hipMemsetAsync(counts, 0, (size_t)N * sizeof(int), stream);
    hipMemsetAsync(diag, 0, (size_t)N * sizeof(float), stream);
    hipMemsetAsync(bar, 0, 2 * sizeof(unsigned), stream);
    hipMemsetAsync(cv, 0, cv_entries * sizeof(int2), stream);
    hist_kernel<<<2048, 256, 0, stream>>>(rows, cols, vals, counts, diag, nnz);
    tile_reduce_kernel<<<T, 256, 0, stream>>>(counts, tile_sums, N);
    tile_scan_kernel<<<1, 1024, 0, stream>>>(tile_sums, tile_off, &row_ptr[N], T);
    tile_apply_kernel<<<T, 1024, 0, stream>>>(counts, tile_off, row_ptr, cursor, N);
    scatter_kernel<<<2048, 256, 0, stream>>>(rows, cols, vals, cursor, cv, nnz);

    // Persistent path requires all blocks co-resident (custom grid barrier).
    int waves = (N + RPW - 1) / RPW;
    int pblocks = (waves + 3) / 4;
    int occ = 0;
    hipOccupancyMaxActiveBlocksPerMultiprocessor(&occ, cheb_persistent, 256, 0);
    bool use_persist = (occ > 0) && ((long)occ * NUM_CU >= (long)pblocks);

    if (use_persist) {
        cheb_persistent<<<pblocks, 256, 0, stream>>>(X, B0, B1, acc, row_ptr, cv,
                                                     diag, bar, bar + 1, co, N);
    } else {
        int nblk = (N + 3) >> 2;
        cheb_first<<<nblk, 256, 0, stream>>>(X, B0, acc, row_ptr, cv, diag,
                                             (float)c[0], (float)c[1], N);
        cheb_step<<<nblk, 256, 0, stream>>>(X, B0, B1, acc, row_ptr, cv, diag,
                                            (float)c[2], N);
        const float* t0p = B0;
        const float* t1p = B1;
        for (int k = 3; k < CHEB_M; ++k) {
            cheb_step<<<nblk, 256, 0, stream>>>(t0p, t1p, (float*)t0p, acc, row_ptr,
                                                cv, diag, (float)c[k], N);
            const float* tmp = t0p; t0p = t1p; t1p = tmp;
        }
    }
}